// Round 1
// baseline (97.929 us; speedup 1.0000x reference)
//
#include <hip/hip_runtime.h>

// DepthToSpace, BLOCK_SIZE=2
// in : x[B=16][C=256][H=128][W=128] f32   (C = (i*2+k)*64 + dd)
// out: y[B=16][d=64][2H=256][2W=256] f32
// out[b, dd, h*2+i, w*2+k] = x[b, (i*2+k)*64 + dd, h, w]
//
// Each thread produces 4 consecutive output floats (one float4):
//   out cols W4*4 .. W4*4+3  ->  (w0,k=0),(w0,k=1),(w0+1,k=0),(w0+1,k=1)
// i.e. float2 from channel c0 = i*128+dd and float2 from c1 = c0+64,
// interleaved. Reads: 8B/lane coalesced x2 streams. Writes: 16B/lane coalesced.

__global__ __launch_bounds__(256) void d2s_kernel(const float* __restrict__ x,
                                                  float* __restrict__ out,
                                                  int n4) {
    int t = blockIdx.x * blockDim.x + threadIdx.x;
    if (t >= n4) return;

    // decompose t over output float4 index space:
    //   t = ((b*64 + dd)*256 + H)*64 + W4        (W4 = output col / 4)
    int W4 = t & 63;
    int H  = (t >> 6) & 255;
    int dd = (t >> 14) & 63;
    int b  = t >> 20;

    int h  = H >> 1;
    int i  = H & 1;
    int w0 = W4 << 1;

    // input channel for k=0: c0 = i*128 + dd ; for k=1: c0 + 64
    int c0 = (i << 7) + dd;
    // input flat offset: ((b*256 + c)*128 + h)*128 + w
    int base = (b << 22) + (c0 << 14) + (h << 7) + w0;   // fits in int (< 2^26)

    float2 a = *reinterpret_cast<const float2*>(x + base);              // k=0 channel
    float2 c = *reinterpret_cast<const float2*>(x + base + (64 << 14)); // k=1 channel

    float4 o;
    o.x = a.x;  // (w0,   k=0)
    o.y = c.x;  // (w0,   k=1)
    o.z = a.y;  // (w0+1, k=0)
    o.w = c.y;  // (w0+1, k=1)
    reinterpret_cast<float4*>(out)[t] = o;
}

extern "C" void kernel_launch(void* const* d_in, const int* in_sizes, int n_in,
                              void* d_out, int out_size, void* d_ws, size_t ws_size,
                              hipStream_t stream) {
    const float* x = (const float*)d_in[0];
    float* out = (float*)d_out;
    int n4 = out_size / 4;                 // 16,777,216 float4 stores
    int block = 256;
    int grid = (n4 + block - 1) / block;   // 65536 blocks
    d2s_kernel<<<grid, block, 0, stream>>>(x, out, n4);
}